// Round 2
// baseline (597.562 us; speedup 1.0000x reference)
//
#include <hip/hip_runtime.h>

#define D_DIM 1024
#define H_DIM 64
#define T_SEQ 2048
#define B_SZ 8
#define M_TOT (B_SZ * T_SEQ)   // 16384 rows

// ---------------------------------------------------------------------------
// Kernel 1: fused QKV projection.
// C[m][c] = sum_d x[m][d] * W[d][c] with W = [Wq | Wk | Wv] (192 cols).
// Block: 64 rows x 192 cols, BK=16, 256 threads, 4x12 register tile/thread.
// ---------------------------------------------------------------------------
__global__ __launch_bounds__(256) void qkv_proj_kernel(
    const float* __restrict__ x, const float* __restrict__ Wq,
    const float* __restrict__ Wk, const float* __restrict__ Wv,
    float* __restrict__ Q, float* __restrict__ K, float* __restrict__ V)
{
    __shared__ float xs[64][20];    // pad 16->20: row stride 80B (16B aligned, banks spread)
    __shared__ float ws[16][192];

    const int tid = threadIdx.x;
    const int m0  = blockIdx.x * 64;
    const int tr  = tid >> 4;       // 0..15 (4 rows each)
    const int tc  = tid & 15;       // 0..15 (12 cols each)

    float acc[4][12];
    #pragma unroll
    for (int i = 0; i < 4; ++i)
        #pragma unroll
        for (int j = 0; j < 12; ++j) acc[i][j] = 0.f;

    for (int k0 = 0; k0 < D_DIM; k0 += 16) {
        // --- stage x tile: 64x16 floats, one float4 per thread, coalesced ---
        {
            const int r  = tid >> 2;
            const int c4 = (tid & 3) * 4;
            float4 v = *reinterpret_cast<const float4*>(
                &x[(size_t)(m0 + r) * D_DIM + k0 + c4]);
            *reinterpret_cast<float4*>(&xs[r][c4]) = v;
        }
        // --- stage W tile: 16x192 floats = 768 float4, 3 per thread ---
        #pragma unroll
        for (int j = 0; j < 3; ++j) {
            const int idx = tid * 3 + j;       // 0..767
            const int kk  = idx / 48;          // 0..15
            const int c   = (idx % 48) * 4;    // 0..188
            const float* src = (c < 64)  ? &Wq[(size_t)(k0 + kk) * H_DIM + c]
                             : (c < 128) ? &Wk[(size_t)(k0 + kk) * H_DIM + (c - 64)]
                                         : &Wv[(size_t)(k0 + kk) * H_DIM + (c - 128)];
            *reinterpret_cast<float4*>(&ws[kk][c]) =
                *reinterpret_cast<const float4*>(src);
        }
        __syncthreads();

        #pragma unroll
        for (int kk = 0; kk < 16; ++kk) {
            float a[4], b[12];
            #pragma unroll
            for (int i = 0; i < 4; ++i) a[i] = xs[tr * 4 + i][kk];
            #pragma unroll
            for (int j = 0; j < 12; ++j) b[j] = ws[kk][tc * 12 + j];  // 48B aligned -> 3x ds_read_b128
            #pragma unroll
            for (int i = 0; i < 4; ++i)
                #pragma unroll
                for (int j = 0; j < 12; ++j)
                    acc[i][j] = fmaf(a[i], b[j], acc[i][j]);
        }
        __syncthreads();
    }

    // epilogue: scatter into Q/K/V (col tile may straddle matrix boundaries)
    #pragma unroll
    for (int i = 0; i < 4; ++i) {
        const int row = m0 + tr * 4 + i;
        #pragma unroll
        for (int j = 0; j < 12; ++j) {
            const int c = tc * 12 + j;
            const float v = acc[i][j];
            if (c < 64)       Q[(size_t)row * H_DIM + c]         = v;
            else if (c < 128) K[(size_t)row * H_DIM + (c - 64)]  = v;
            else              V[(size_t)row * H_DIM + (c - 128)] = v;
        }
    }
}

// ---------------------------------------------------------------------------
// Kernel 2: causal flash attention, fp32.
// Block = 64 query rows (lane = row), 4 waves split keys interleaved
// (wave w takes keys w*16..w*16+15 of each 64-key tile). Q row and output
// accumulator in registers; K/V LDS reads are all-lane broadcasts.
// Cross-wave (m,l,acc) merge via LDS at the end.
// ---------------------------------------------------------------------------
__global__ __launch_bounds__(256, 1) void attn_kernel(
    const float* __restrict__ Q, const float* __restrict__ K,
    const float* __restrict__ V, float* __restrict__ out)
{
    __shared__ float Kl[64][68];   // pad to 68: 272B row stride, 16B aligned
    __shared__ float Vl[64][68];
    __shared__ float mred[4][64];
    __shared__ float lred[4][64];

    const int tid  = threadIdx.x;
    const int lane = tid & 63;
    const int w    = tid >> 6;          // wave 0..3
    const int b    = blockIdx.x >> 5;   // batch
    const int qt   = blockIdx.x & 31;   // q tile
    const int q0   = qt * 64;
    const int row  = q0 + lane;         // query row within batch

    const float* Qb = Q + (size_t)b * T_SEQ * H_DIM;
    const float* Kb = K + (size_t)b * T_SEQ * H_DIM;
    const float* Vb = V + (size_t)b * T_SEQ * H_DIM;

    // Q row -> registers (64 floats)
    float4 qv[16];
    #pragma unroll
    for (int i = 0; i < 16; ++i)
        qv[i] = reinterpret_cast<const float4*>(&Qb[(size_t)row * H_DIM])[i];

    float4 av[16];
    #pragma unroll
    for (int i = 0; i < 16; ++i) av[i] = make_float4(0.f, 0.f, 0.f, 0.f);
    float m = -1e30f, l = 0.f;

    const int ntiles = qt + 1;   // causal: keys 0 .. q0+63
    for (int t = 0; t < ntiles; ++t) {
        const int k0 = t * 64;
        // cooperative load of K,V 64x64 tiles (coalesced float4)
        {
            const int r  = tid >> 2;
            const int c4 = (tid & 3) * 4;
            #pragma unroll
            for (int rep = 0; rep < 4; ++rep) {
                const int cc = c4 + rep * 16;
                *reinterpret_cast<float4*>(&Kl[r][cc]) =
                    *reinterpret_cast<const float4*>(&Kb[(size_t)(k0 + r) * H_DIM + cc]);
                *reinterpret_cast<float4*>(&Vl[r][cc]) =
                    *reinterpret_cast<const float4*>(&Vb[(size_t)(k0 + r) * H_DIM + cc]);
            }
        }
        __syncthreads();

        // scores for this wave's 16 keys
        float s[16];
        float tmax = -1e30f;
        #pragma unroll 4
        for (int jj = 0; jj < 16; ++jj) {
            const int kk = (w << 4) + jj;
            const int kg = k0 + kk;
            const float4* kr = reinterpret_cast<const float4*>(&Kl[kk][0]);
            float s0 = 0.f, s1 = 0.f, s2 = 0.f, s3 = 0.f;
            #pragma unroll
            for (int h = 0; h < 16; ++h) {
                const float4 kvv = kr[h];
                s0 = fmaf(qv[h].x, kvv.x, s0);
                s1 = fmaf(qv[h].y, kvv.y, s1);
                s2 = fmaf(qv[h].z, kvv.z, s2);
                s3 = fmaf(qv[h].w, kvv.w, s3);
            }
            float sv = ((s0 + s1) + (s2 + s3)) * 0.125f;
            sv = (kg <= row) ? sv : -1e30f;      // causal mask (explicit predicate)
            s[jj] = sv;
            tmax  = fmaxf(tmax, sv);
        }

        // online softmax rescale (once per 16-key tile)
        const float mnew = fmaxf(m, tmax);
        if (mnew > m) {
            const float scale = __expf(m - mnew);   // m==-1e30 -> underflow to 0, acc/l are 0 anyway
            #pragma unroll
            for (int h = 0; h < 16; ++h) {
                av[h].x *= scale; av[h].y *= scale;
                av[h].z *= scale; av[h].w *= scale;
            }
            l *= scale;        // <<< FIX: denominator terms are relative to old max too
            m = mnew;
        }

        // P*V accumulate
        #pragma unroll 4
        for (int jj = 0; jj < 16; ++jj) {
            const int kk = (w << 4) + jj;
            const float p = (s[jj] > -1e29f) ? __expf(s[jj] - m) : 0.f;
            l += p;
            const float4* vr = reinterpret_cast<const float4*>(&Vl[kk][0]);
            #pragma unroll
            for (int h = 0; h < 16; ++h) {
                const float4 vv = vr[h];
                av[h].x = fmaf(p, vv.x, av[h].x);
                av[h].y = fmaf(p, vv.y, av[h].y);
                av[h].z = fmaf(p, vv.z, av[h].z);
                av[h].w = fmaf(p, vv.w, av[h].w);
            }
        }
        __syncthreads();   // before next tile overwrites Kl/Vl
    }

    // -------- cross-wave merge --------
    mred[w][lane] = m;
    lred[w][lane] = l;
    __syncthreads();

    const float M = fmaxf(fmaxf(mred[0][lane], mred[1][lane]),
                          fmaxf(mred[2][lane], mred[3][lane]));
    const float alpha = __expf(m - M);   // m==-1e30 (no valid keys in this wave) -> 0

    // sequential accumulation of scaled acc into Kl (reused as ob[64][68])
    if (w == 0) {
        #pragma unroll
        for (int h = 0; h < 16; ++h) {
            float4 o = make_float4(av[h].x * alpha, av[h].y * alpha,
                                   av[h].z * alpha, av[h].w * alpha);
            *reinterpret_cast<float4*>(&Kl[lane][h * 4]) = o;
        }
    }
    __syncthreads();
    #pragma unroll
    for (int ww = 1; ww < 4; ++ww) {
        if (w == ww) {
            #pragma unroll
            for (int h = 0; h < 16; ++h) {
                float4 cur = *reinterpret_cast<float4*>(&Kl[lane][h * 4]);
                cur.x += av[h].x * alpha; cur.y += av[h].y * alpha;
                cur.z += av[h].z * alpha; cur.w += av[h].w * alpha;
                *reinterpret_cast<float4*>(&Kl[lane][h * 4]) = cur;
            }
        }
        __syncthreads();
    }

    // final normalize + coalesced store: thread -> (row tid>>2, 16 dims)
    {
        const int rr = tid >> 2;
        const int d0 = (tid & 3) * 16;
        const float Mr = fmaxf(fmaxf(mred[0][rr], mred[1][rr]),
                               fmaxf(mred[2][rr], mred[3][rr]));
        float Lr = 0.f;
        #pragma unroll
        for (int ww = 0; ww < 4; ++ww)
            Lr += lred[ww][rr] * __expf(mred[ww][rr] - Mr);
        const float inv = 1.f / Lr;   // always >0: key 0 is valid for every row

        #pragma unroll
        for (int h4 = 0; h4 < 4; ++h4) {
            float4 o = *reinterpret_cast<float4*>(&Kl[rr][d0 + h4 * 4]);
            o.x *= inv; o.y *= inv; o.z *= inv; o.w *= inv;
            *reinterpret_cast<float4*>(
                &out[((size_t)b * T_SEQ + q0 + rr) * H_DIM + d0 + h4 * 4]) = o;
        }
    }
}

// ---------------------------------------------------------------------------
extern "C" void kernel_launch(void* const* d_in, const int* in_sizes, int n_in,
                              void* d_out, int out_size, void* d_ws, size_t ws_size,
                              hipStream_t stream) {
    const float* x  = (const float*)d_in[0];
    const float* Wq = (const float*)d_in[1];
    const float* Wk = (const float*)d_in[2];
    const float* Wv = (const float*)d_in[3];

    float* Q = (float*)d_ws;                       // 16384*64 fp32 = 4 MB
    float* K = Q + (size_t)M_TOT * H_DIM;
    float* V = K + (size_t)M_TOT * H_DIM;
    float* o = (float*)d_out;

    qkv_proj_kernel<<<M_TOT / 64, 256, 0, stream>>>(x, Wq, Wk, Wv, Q, K, V);
    attn_kernel<<<B_SZ * (T_SEQ / 64), 256, 0, stream>>>(Q, K, V, o);
}

// Round 4
// 68.535 us; speedup vs baseline: 8.7191x; 8.7191x over previous
//
#include <hip/hip_runtime.h>

#define D_DIM 1024
#define H_DIM 64
#define T_SEQ 2048
#define B_SZ  8
#define M_TOT (B_SZ * T_SEQ)

typedef __attribute__((ext_vector_type(4))) float f32x4;
typedef __attribute__((ext_vector_type(8))) short s16x8;
typedef __attribute__((ext_vector_type(8))) unsigned short u16x8;
typedef __attribute__((ext_vector_type(4))) unsigned short u16x4;

__device__ __forceinline__ unsigned short f2bf(float x) {
    union { float f; unsigned u; } v; v.f = x;
    unsigned r = (v.u + 0x7FFFu + ((v.u >> 16) & 1u)) >> 16;   // RNE
    return (unsigned short)r;
}
__device__ __forceinline__ float bf2f(unsigned short u) {
    union { unsigned u; float f; } v; v.u = ((unsigned)u) << 16; return v.f;
}

__device__ __forceinline__ f32x4 mfma_bf16(u16x8 a, u16x8 b, f32x4 c) {
    return __builtin_amdgcn_mfma_f32_16x16x32_bf16(
        __builtin_bit_cast(s16x8, a), __builtin_bit_cast(s16x8, b), c, 0, 0, 0);
}

// ---------------------------------------------------------------------------
// Kernel 0: W [1024][64] fp32 (x3) -> Wt bf16 [192][1024]  (Wt[c][k] = W[k][c])
// ---------------------------------------------------------------------------
__global__ __launch_bounds__(256) void wtrans_kernel(
    const float* __restrict__ Wq, const float* __restrict__ Wk,
    const float* __restrict__ Wv, unsigned short* __restrict__ Wt)
{
    __shared__ unsigned short tw[64 * 72];
    const int mat = blockIdx.x / 16;
    const int k0  = (blockIdx.x % 16) * 64;
    const float* W = (mat == 0) ? Wq : (mat == 1) ? Wk : Wv;
    const int tid = threadIdx.x;

    {   // read 64x64 fp32 tile coalesced, convert, store row-major in LDS
        const int r = tid >> 2, c0 = (tid & 3) * 16;
        #pragma unroll
        for (int jj = 0; jj < 4; ++jj) {
            float4 v = *reinterpret_cast<const float4*>(&W[(size_t)(k0 + r) * H_DIM + c0 + jj * 4]);
            u16x4 u = { f2bf(v.x), f2bf(v.y), f2bf(v.z), f2bf(v.w) };
            *reinterpret_cast<u16x4*>(&tw[r * 72 + c0 + jj * 4]) = u;
        }
    }
    __syncthreads();
    {   // transposed read, coalesced global write
        const int c = tid >> 2, kc = (tid & 3) * 16;
        unsigned short tmp[16];
        #pragma unroll
        for (int kk = 0; kk < 16; ++kk) tmp[kk] = tw[(kc + kk) * 72 + c];
        #pragma unroll
        for (int h = 0; h < 2; ++h)
            *reinterpret_cast<u16x8*>(&Wt[((size_t)mat * 64 + c) * D_DIM + k0 + kc + h * 8]) =
                *reinterpret_cast<u16x8*>(&tmp[h * 8]);
    }
}

// ---------------------------------------------------------------------------
// Kernel 1: QKV projection, bf16 MFMA.  (unchanged from round 3)
// ---------------------------------------------------------------------------
__global__ __launch_bounds__(256) void qkv_proj_kernel(
    const float* __restrict__ x, const unsigned short* __restrict__ Wt,
    unsigned short* __restrict__ Qg, unsigned short* __restrict__ Kg,
    unsigned short* __restrict__ Vtg)
{
    __shared__ unsigned short xs[64 * 40];
    __shared__ unsigned short ws[192 * 40];
    __shared__ unsigned short vt[64 * 72];

    const int tid = threadIdx.x;
    const int w = tid >> 6, l = tid & 63, g = l >> 4, n = l & 15;
    const int m0 = blockIdx.x * 64;

    f32x4 acc[4][3];
    #pragma unroll
    for (int rb = 0; rb < 4; ++rb)
        #pragma unroll
        for (int ct = 0; ct < 3; ++ct) acc[rb][ct] = f32x4{0.f, 0.f, 0.f, 0.f};

    float4 xr0, xr1;
    u16x8  wr[3];
    const int sr = tid >> 2, sc = (tid & 3) * 8;
    {
        xr0 = *reinterpret_cast<const float4*>(&x[(size_t)(m0 + sr) * D_DIM + sc]);
        xr1 = *reinterpret_cast<const float4*>(&x[(size_t)(m0 + sr) * D_DIM + sc + 4]);
        #pragma unroll
        for (int jj = 0; jj < 3; ++jj) {
            int u = tid + jj * 256, r = u >> 2, c = (u & 3) * 8;
            wr[jj] = *reinterpret_cast<const u16x8*>(&Wt[(size_t)r * D_DIM + c]);
        }
    }

    for (int ks = 0; ks < 32; ++ks) {
        __syncthreads();
        {
            u16x8 xv = { f2bf(xr0.x), f2bf(xr0.y), f2bf(xr0.z), f2bf(xr0.w),
                         f2bf(xr1.x), f2bf(xr1.y), f2bf(xr1.z), f2bf(xr1.w) };
            *reinterpret_cast<u16x8*>(&xs[sr * 40 + sc]) = xv;
            #pragma unroll
            for (int jj = 0; jj < 3; ++jj) {
                int u = tid + jj * 256, r = u >> 2, c = (u & 3) * 8;
                *reinterpret_cast<u16x8*>(&ws[r * 40 + c]) = wr[jj];
            }
        }
        __syncthreads();
        if (ks < 31) {
            const int k0 = (ks + 1) * 32;
            xr0 = *reinterpret_cast<const float4*>(&x[(size_t)(m0 + sr) * D_DIM + k0 + sc]);
            xr1 = *reinterpret_cast<const float4*>(&x[(size_t)(m0 + sr) * D_DIM + k0 + sc + 4]);
            #pragma unroll
            for (int jj = 0; jj < 3; ++jj) {
                int u = tid + jj * 256, r = u >> 2, c = (u & 3) * 8;
                wr[jj] = *reinterpret_cast<const u16x8*>(&Wt[(size_t)r * D_DIM + k0 + c]);
            }
        }
        u16x8 af[4], bfr[3];
        #pragma unroll
        for (int rb = 0; rb < 4; ++rb)
            af[rb] = *reinterpret_cast<const u16x8*>(&xs[(rb * 16 + n) * 40 + g * 8]);
        #pragma unroll
        for (int ct = 0; ct < 3; ++ct)
            bfr[ct] = *reinterpret_cast<const u16x8*>(&ws[(w * 48 + ct * 16 + n) * 40 + g * 8]);
        #pragma unroll
        for (int rb = 0; rb < 4; ++rb)
            #pragma unroll
            for (int ct = 0; ct < 3; ++ct)
                acc[rb][ct] = mfma_bf16(af[rb], bfr[ct], acc[rb][ct]);
    }

    const int b = m0 >> 11, t0 = m0 & (T_SEQ - 1);
    #pragma unroll
    for (int rb = 0; rb < 4; ++rb)
        #pragma unroll
        for (int ct = 0; ct < 3; ++ct) {
            const int c = w * 48 + ct * 16 + n;
            #pragma unroll
            for (int r = 0; r < 4; ++r) {
                const int mrow = m0 + rb * 16 + g * 4 + r;
                const float val = acc[rb][ct][r];
                if (c < 64)
                    Qg[(size_t)mrow * H_DIM + c] = f2bf(val * 0.125f);
                else if (c < 128)
                    Kg[(size_t)mrow * H_DIM + (c - 64)] = f2bf(val);
                else
                    vt[(c - 128) * 72 + (rb * 16 + g * 4 + r)] = f2bf(val);
            }
        }
    __syncthreads();
    for (int u = tid; u < 512; u += 256) {
        const int h = u >> 3, c8 = (u & 7) * 8;
        *reinterpret_cast<u16x8*>(&Vtg[((size_t)(b * 64 + h)) * T_SEQ + t0 + c8]) =
            *reinterpret_cast<const u16x8*>(&vt[h * 72 + c8]);
    }
}

// ---------------------------------------------------------------------------
// Kernel 2: causal flash attention, bf16 MFMA.
// QK^T swapped (S^T = K*Q).  PV now ALSO swapped: O^T = V^T * P^T, so each
// lane's D column is its OWN query -> no cross-lane l shuffle, and the
// store is a contiguous float4 at out[qrow][hb*16+4g].
// ---------------------------------------------------------------------------
__global__ __launch_bounds__(128) void attn_kernel(
    const unsigned short* __restrict__ Qg, const unsigned short* __restrict__ Kg,
    const unsigned short* __restrict__ Vtg, float* __restrict__ out)
{
    __shared__ unsigned short Kl[64 * 72];   // [key][h]
    __shared__ unsigned short Vl[64 * 72];   // [h][key]

    const int tid = threadIdx.x;
    const int wv = tid >> 6, l = tid & 63, g = l >> 4, n = l & 15;

    const int i = blockIdx.x, hi = i >> 8, rest = i & 255;
    const int b = hi * 4 + (rest >> 6), j = rest & 63;
    const int qt = hi ? (63 - j) : j;
    const int q0 = qt * 32;
    const int qrow = q0 + wv * 16 + n;
    const int nk = (qt >> 1) + 1;

    const unsigned short* Qb = Qg + (size_t)b * T_SEQ * H_DIM;
    const unsigned short* Kb = Kg + (size_t)b * T_SEQ * H_DIM;
    const unsigned short* Vb = Vtg + (size_t)b * H_DIM * T_SEQ;

    const u16x8 qf0 = *reinterpret_cast<const u16x8*>(&Qb[(size_t)qrow * H_DIM + g * 8]);
    const u16x8 qf1 = *reinterpret_cast<const u16x8*>(&Qb[(size_t)qrow * H_DIM + 32 + g * 8]);

    f32x4 oacc[4];
    #pragma unroll
    for (int hb = 0; hb < 4; ++hb) oacc[hb] = f32x4{0.f, 0.f, 0.f, 0.f};
    float mrun = -1e30f, lrun = 0.f;

    u16x8 kst[4], vst[4];
    #pragma unroll
    for (int ii = 0; ii < 4; ++ii) {
        const int u = tid + ii * 128, r = u >> 3, c = (u & 7) * 8;
        kst[ii] = *reinterpret_cast<const u16x8*>(&Kb[(size_t)r * H_DIM + c]);
        vst[ii] = *reinterpret_cast<const u16x8*>(&Vb[(size_t)r * T_SEQ + c]);
    }

    for (int t = 0; t < nk; ++t) {
        __syncthreads();
        #pragma unroll
        for (int ii = 0; ii < 4; ++ii) {
            const int u = tid + ii * 128, r = u >> 3, c = (u & 7) * 8;
            *reinterpret_cast<u16x8*>(&Kl[r * 72 + c]) = kst[ii];
            *reinterpret_cast<u16x8*>(&Vl[r * 72 + c]) = vst[ii];
        }
        __syncthreads();
        if (t + 1 < nk) {
            const int k0n = (t + 1) * 64;
            #pragma unroll
            for (int ii = 0; ii < 4; ++ii) {
                const int u = tid + ii * 128, r = u >> 3, c = (u & 7) * 8;
                kst[ii] = *reinterpret_cast<const u16x8*>(&Kb[(size_t)(k0n + r) * H_DIM + c]);
                vst[ii] = *reinterpret_cast<const u16x8*>(&Vb[(size_t)r * T_SEQ + k0n + c]);
            }
        }
        const int k0 = t * 64;

        // ---- swapped QK^T: S^T[key][q] ----
        f32x4 s[4];
        #pragma unroll
        for (int kb = 0; kb < 4; ++kb) {
            const u16x8 kf0 = *reinterpret_cast<const u16x8*>(&Kl[(kb * 16 + n) * 72 + g * 8]);
            const u16x8 kf1 = *reinterpret_cast<const u16x8*>(&Kl[(kb * 16 + n) * 72 + 32 + g * 8]);
            f32x4 z = f32x4{0.f, 0.f, 0.f, 0.f};
            z = mfma_bf16(kf0, qf0, z);
            z = mfma_bf16(kf1, qf1, z);
            s[kb] = z;
        }

        // ---- mask + online softmax ----
        float sv[16];
        float tmax = -1e30f;
        #pragma unroll
        for (int kb = 0; kb < 4; ++kb)
            #pragma unroll
            for (int r = 0; r < 4; ++r) {
                const int kk = k0 + kb * 16 + g * 4 + r;
                float v = s[kb][r];
                v = (kk <= qrow) ? v : -1e30f;
                sv[kb * 4 + r] = v;
                tmax = fmaxf(tmax, v);
            }
        tmax = fmaxf(tmax, __shfl_xor(tmax, 16));
        tmax = fmaxf(tmax, __shfl_xor(tmax, 32));
        const float mnew = fmaxf(mrun, tmax);
        const float scale = __expf(mrun - mnew);
        #pragma unroll
        for (int hb = 0; hb < 4; ++hb) oacc[hb] *= scale;
        lrun = lrun * scale;
        mrun = mnew;

        unsigned short pb[16];
        float ps = 0.f;
        #pragma unroll
        for (int q = 0; q < 16; ++q) {
            const float p = __expf(sv[q] - mnew);
            pb[q] = f2bf(p);
            ps += bf2f(pb[q]);          // denominator = exactly the weights PV uses
        }
        ps += __shfl_xor(ps, 16);
        ps += __shfl_xor(ps, 32);
        lrun += ps;

        u16x8 pa0, pa1;
        #pragma unroll
        for (int q = 0; q < 8; ++q) { pa0[q] = pb[q]; pa1[q] = pb[8 + q]; }

        // ---- PV, operand-swapped: O^T = V^T * P^T ----
        // A = V^T rows (h), B = P^T cols (query n) -> D[row 4g+r][col n]
        // = O[query n][h = hb*16 + 4g + r]: lane-local query, contiguous h.
        #pragma unroll
        for (int hb = 0; hb < 4; ++hb) {
            const unsigned short* vp = &Vl[(hb * 16 + n) * 72 + 4 * g];
            const u16x4 a0 = *reinterpret_cast<const u16x4*>(vp);
            const u16x4 a1 = *reinterpret_cast<const u16x4*>(vp + 16);
            const u16x4 b0 = *reinterpret_cast<const u16x4*>(vp + 32);
            const u16x4 b1 = *reinterpret_cast<const u16x4*>(vp + 48);
            const u16x8 vf0 = { a0[0], a0[1], a0[2], a0[3], a1[0], a1[1], a1[2], a1[3] };
            const u16x8 vf1 = { b0[0], b0[1], b0[2], b0[3], b1[0], b1[1], b1[2], b1[3] };
            oacc[hb] = mfma_bf16(vf0, pa0, oacc[hb]);
            oacc[hb] = mfma_bf16(vf1, pa1, oacc[hb]);
        }
    }

    // ---- normalize + store: lane-local query, contiguous float4 per hb ----
    const float inv = 1.0f / lrun;
    #pragma unroll
    for (int hb = 0; hb < 4; ++hb) {
        float4 o;
        o.x = oacc[hb][0] * inv; o.y = oacc[hb][1] * inv;
        o.z = oacc[hb][2] * inv; o.w = oacc[hb][3] * inv;
        *reinterpret_cast<float4*>(
            &out[((size_t)b * T_SEQ + qrow) * H_DIM + hb * 16 + 4 * g]) = o;
    }
}

// ---------------------------------------------------------------------------
extern "C" void kernel_launch(void* const* d_in, const int* in_sizes, int n_in,
                              void* d_out, int out_size, void* d_ws, size_t ws_size,
                              hipStream_t stream) {
    const float* x  = (const float*)d_in[0];
    const float* Wq = (const float*)d_in[1];
    const float* Wk = (const float*)d_in[2];
    const float* Wv = (const float*)d_in[3];

    unsigned short* Qg  = (unsigned short*)d_ws;
    unsigned short* Kg  = Qg + (size_t)M_TOT * H_DIM;
    unsigned short* Vtg = Kg + (size_t)M_TOT * H_DIM;
    unsigned short* Wt  = Vtg + (size_t)M_TOT * H_DIM;
    float* o = (float*)d_out;

    wtrans_kernel<<<48, 256, 0, stream>>>(Wq, Wk, Wv, Wt);
    qkv_proj_kernel<<<M_TOT / 64, 256, 0, stream>>>(x, Wt, Qg, Kg, Vtg);
    attn_kernel<<<512, 128, 0, stream>>>(Qg, Kg, Vtg, o);
}

// Round 5
// 62.434 us; speedup vs baseline: 9.5711x; 1.0977x over previous
//
#include <hip/hip_runtime.h>

#define D_DIM 1024
#define H_DIM 64
#define T_SEQ 2048
#define B_SZ  8
#define M_TOT (B_SZ * T_SEQ)

typedef __attribute__((ext_vector_type(4))) float f32x4;
typedef __attribute__((ext_vector_type(8))) short s16x8;
typedef __attribute__((ext_vector_type(8))) unsigned short u16x8;
typedef __attribute__((ext_vector_type(4))) unsigned short u16x4;

__device__ __forceinline__ unsigned short f2bf(float x) {
    union { float f; unsigned u; } v; v.f = x;
    unsigned r = (v.u + 0x7FFFu + ((v.u >> 16) & 1u)) >> 16;   // RNE
    return (unsigned short)r;
}
__device__ __forceinline__ float bf2f(unsigned short u) {
    union { unsigned u; float f; } v; v.u = ((unsigned)u) << 16; return v.f;
}

__device__ __forceinline__ f32x4 mfma_bf16(u16x8 a, u16x8 b, f32x4 c) {
    return __builtin_amdgcn_mfma_f32_16x16x32_bf16(
        __builtin_bit_cast(s16x8, a), __builtin_bit_cast(s16x8, b), c, 0, 0, 0);
}

// ---------------------------------------------------------------------------
// Kernel 0: W [1024][64] fp32 (x3) -> Wt bf16 [192][1024]  (Wt[c][k] = W[k][c])
// ---------------------------------------------------------------------------
__global__ __launch_bounds__(256) void wtrans_kernel(
    const float* __restrict__ Wq, const float* __restrict__ Wk,
    const float* __restrict__ Wv, unsigned short* __restrict__ Wt)
{
    __shared__ unsigned short tw[64 * 72];
    const int mat = blockIdx.x / 16;
    const int k0  = (blockIdx.x % 16) * 64;
    const float* W = (mat == 0) ? Wq : (mat == 1) ? Wk : Wv;
    const int tid = threadIdx.x;

    {
        const int r = tid >> 2, c0 = (tid & 3) * 16;
        #pragma unroll
        for (int jj = 0; jj < 4; ++jj) {
            float4 v = *reinterpret_cast<const float4*>(&W[(size_t)(k0 + r) * H_DIM + c0 + jj * 4]);
            u16x4 u = { f2bf(v.x), f2bf(v.y), f2bf(v.z), f2bf(v.w) };
            *reinterpret_cast<u16x4*>(&tw[r * 72 + c0 + jj * 4]) = u;
        }
    }
    __syncthreads();
    {
        const int c = tid >> 2, kc = (tid & 3) * 16;
        unsigned short tmp[16];
        #pragma unroll
        for (int kk = 0; kk < 16; ++kk) tmp[kk] = tw[(kc + kk) * 72 + c];
        #pragma unroll
        for (int h = 0; h < 2; ++h)
            *reinterpret_cast<u16x8*>(&Wt[((size_t)mat * 64 + c) * D_DIM + k0 + kc + h * 8]) =
                *reinterpret_cast<u16x8*>(&tmp[h * 8]);
    }
}

// ---------------------------------------------------------------------------
// Kernel 1: QKV projection, bf16 MFMA.  v2: 32-row tiles (grid 512), BK=64.
// Block: 32 rows x 192 cols, 4 waves (48 cols each), reg-staged dbuf.
// LDS stride 88 u16 (176B, 16B-aligned, bank-spread).
// ---------------------------------------------------------------------------
__global__ __launch_bounds__(256) void qkv_proj_kernel(
    const float* __restrict__ x, const unsigned short* __restrict__ Wt,
    unsigned short* __restrict__ Qg, unsigned short* __restrict__ Kg,
    unsigned short* __restrict__ Vtg)
{
    __shared__ unsigned short xs[32 * 88];    // [32][64+pad]
    __shared__ unsigned short ws[192 * 88];   // [192][64+pad]
    __shared__ unsigned short vt[64 * 40];    // epilogue V transpose [h][32t+pad]

    const int tid = threadIdx.x;
    const int w = tid >> 6, l = tid & 63, g = l >> 4, n = l & 15;
    const int m0 = blockIdx.x * 32;

    f32x4 acc[2][3];
    #pragma unroll
    for (int rb = 0; rb < 2; ++rb)
        #pragma unroll
        for (int ct = 0; ct < 3; ++ct) acc[rb][ct] = f32x4{0.f, 0.f, 0.f, 0.f};

    // staging registers: x 32x64 fp32 (2 float4/thread), W 192x64 bf16 (6 u16x8/thread)
    float4 xr0, xr1;
    u16x8  wr[6];
    const int sr = tid >> 3, sc = (tid & 7) * 8;      // x: row 0..31, col 0..56
    {
        const float* xp = &x[(size_t)(m0 + sr) * D_DIM + sc];
        xr0 = *reinterpret_cast<const float4*>(xp);
        xr1 = *reinterpret_cast<const float4*>(xp + 4);
        #pragma unroll
        for (int jj = 0; jj < 6; ++jj) {
            int u = tid + jj * 256, r = u >> 3, c = (u & 7) * 8;
            wr[jj] = *reinterpret_cast<const u16x8*>(&Wt[(size_t)r * D_DIM + c]);
        }
    }

    for (int ks = 0; ks < 16; ++ks) {
        __syncthreads();
        {   // LDS write of staged tile
            u16x8 xv = { f2bf(xr0.x), f2bf(xr0.y), f2bf(xr0.z), f2bf(xr0.w),
                         f2bf(xr1.x), f2bf(xr1.y), f2bf(xr1.z), f2bf(xr1.w) };
            *reinterpret_cast<u16x8*>(&xs[sr * 88 + sc]) = xv;
            #pragma unroll
            for (int jj = 0; jj < 6; ++jj) {
                int u = tid + jj * 256, r = u >> 3, c = (u & 7) * 8;
                *reinterpret_cast<u16x8*>(&ws[r * 88 + c]) = wr[jj];
            }
        }
        __syncthreads();
        if (ks < 15) {   // prefetch next K-tile into registers
            const int k0 = (ks + 1) * 64;
            const float* xp = &x[(size_t)(m0 + sr) * D_DIM + k0 + sc];
            xr0 = *reinterpret_cast<const float4*>(xp);
            xr1 = *reinterpret_cast<const float4*>(xp + 4);
            #pragma unroll
            for (int jj = 0; jj < 6; ++jj) {
                int u = tid + jj * 256, r = u >> 3, c = (u & 7) * 8;
                wr[jj] = *reinterpret_cast<const u16x8*>(&Wt[(size_t)r * D_DIM + k0 + c]);
            }
        }
        // two K=32 sub-steps
        #pragma unroll
        for (int kh = 0; kh < 2; ++kh) {
            u16x8 af[2], bfr[3];
            #pragma unroll
            for (int rb = 0; rb < 2; ++rb)
                af[rb] = *reinterpret_cast<const u16x8*>(&xs[(rb * 16 + n) * 88 + kh * 32 + g * 8]);
            #pragma unroll
            for (int ct = 0; ct < 3; ++ct)
                bfr[ct] = *reinterpret_cast<const u16x8*>(&ws[(w * 48 + ct * 16 + n) * 88 + kh * 32 + g * 8]);
            #pragma unroll
            for (int rb = 0; rb < 2; ++rb)
                #pragma unroll
                for (int ct = 0; ct < 3; ++ct)
                    acc[rb][ct] = mfma_bf16(af[rb], bfr[ct], acc[rb][ct]);
        }
    }

    // epilogue: D layout col = lane&15, row = (lane>>4)*4 + reg
    const int b = m0 >> 11, t0 = m0 & (T_SEQ - 1);
    #pragma unroll
    for (int rb = 0; rb < 2; ++rb)
        #pragma unroll
        for (int ct = 0; ct < 3; ++ct) {
            const int c = w * 48 + ct * 16 + n;
            #pragma unroll
            for (int r = 0; r < 4; ++r) {
                const int rin = rb * 16 + g * 4 + r;     // row in tile, 0..31
                const float val = acc[rb][ct][r];
                if (c < 64)
                    Qg[(size_t)(m0 + rin) * H_DIM + c] = f2bf(val * 0.125f);
                else if (c < 128)
                    Kg[(size_t)(m0 + rin) * H_DIM + (c - 64)] = f2bf(val);
                else
                    vt[(c - 128) * 40 + rin] = f2bf(val);
            }
        }
    __syncthreads();
    // coalesced Vt global write: Vt[b][h][t], 64 h x 32 t = 256 u16x8/8... 1 u16x4/thread? 64*32/8=256 u16x8
    {
        const int h = tid >> 2, c8 = (tid & 3) * 8;
        *reinterpret_cast<u16x8*>(&Vtg[((size_t)(b * 64 + h)) * T_SEQ + t0 + c8]) =
            *reinterpret_cast<const u16x8*>(&vt[h * 40 + c8]);
    }
}

// ---------------------------------------------------------------------------
// Kernel 2: causal flash attention, bf16 MFMA (unchanged from round 3 PASS).
// ---------------------------------------------------------------------------
__global__ __launch_bounds__(128) void attn_kernel(
    const unsigned short* __restrict__ Qg, const unsigned short* __restrict__ Kg,
    const unsigned short* __restrict__ Vtg, float* __restrict__ out)
{
    __shared__ unsigned short Kl[64 * 72];   // [key][h]
    __shared__ unsigned short Vl[64 * 72];   // [h][key]

    const int tid = threadIdx.x;
    const int wv = tid >> 6, l = tid & 63, g = l >> 4, n = l & 15;

    const int i = blockIdx.x, hi = i >> 8, rest = i & 255;
    const int b = hi * 4 + (rest >> 6), j = rest & 63;
    const int qt = hi ? (63 - j) : j;
    const int q0 = qt * 32;
    const int qrow = q0 + wv * 16 + n;
    const int nk = (qt >> 1) + 1;

    const unsigned short* Qb = Qg + (size_t)b * T_SEQ * H_DIM;
    const unsigned short* Kb = Kg + (size_t)b * T_SEQ * H_DIM;
    const unsigned short* Vb = Vtg + (size_t)b * H_DIM * T_SEQ;

    const u16x8 qf0 = *reinterpret_cast<const u16x8*>(&Qb[(size_t)qrow * H_DIM + g * 8]);
    const u16x8 qf1 = *reinterpret_cast<const u16x8*>(&Qb[(size_t)qrow * H_DIM + 32 + g * 8]);

    f32x4 oacc[4];
    #pragma unroll
    for (int hb = 0; hb < 4; ++hb) oacc[hb] = f32x4{0.f, 0.f, 0.f, 0.f};
    float mrun = -1e30f, lrun = 0.f;

    u16x8 kst[4], vst[4];
    #pragma unroll
    for (int ii = 0; ii < 4; ++ii) {
        const int u = tid + ii * 128, r = u >> 3, c = (u & 7) * 8;
        kst[ii] = *reinterpret_cast<const u16x8*>(&Kb[(size_t)r * H_DIM + c]);
        vst[ii] = *reinterpret_cast<const u16x8*>(&Vb[(size_t)r * T_SEQ + c]);
    }

    for (int t = 0; t < nk; ++t) {
        __syncthreads();
        #pragma unroll
        for (int ii = 0; ii < 4; ++ii) {
            const int u = tid + ii * 128, r = u >> 3, c = (u & 7) * 8;
            *reinterpret_cast<u16x8*>(&Kl[r * 72 + c]) = kst[ii];
            *reinterpret_cast<u16x8*>(&Vl[r * 72 + c]) = vst[ii];
        }
        __syncthreads();
        if (t + 1 < nk) {
            const int k0n = (t + 1) * 64;
            #pragma unroll
            for (int ii = 0; ii < 4; ++ii) {
                const int u = tid + ii * 128, r = u >> 3, c = (u & 7) * 8;
                kst[ii] = *reinterpret_cast<const u16x8*>(&Kb[(size_t)(k0n + r) * H_DIM + c]);
                vst[ii] = *reinterpret_cast<const u16x8*>(&Vb[(size_t)r * T_SEQ + k0n + c]);
            }
        }
        const int k0 = t * 64;

        // ---- swapped QK^T: S^T[key][q] ----
        f32x4 s[4];
        #pragma unroll
        for (int kb = 0; kb < 4; ++kb) {
            const u16x8 kf0 = *reinterpret_cast<const u16x8*>(&Kl[(kb * 16 + n) * 72 + g * 8]);
            const u16x8 kf1 = *reinterpret_cast<const u16x8*>(&Kl[(kb * 16 + n) * 72 + 32 + g * 8]);
            f32x4 z = f32x4{0.f, 0.f, 0.f, 0.f};
            z = mfma_bf16(kf0, qf0, z);
            z = mfma_bf16(kf1, qf1, z);
            s[kb] = z;
        }

        // ---- mask + online softmax ----
        float sv[16];
        float tmax = -1e30f;
        #pragma unroll
        for (int kb = 0; kb < 4; ++kb)
            #pragma unroll
            for (int r = 0; r < 4; ++r) {
                const int kk = k0 + kb * 16 + g * 4 + r;
                float v = s[kb][r];
                v = (kk <= qrow) ? v : -1e30f;
                sv[kb * 4 + r] = v;
                tmax = fmaxf(tmax, v);
            }
        tmax = fmaxf(tmax, __shfl_xor(tmax, 16));
        tmax = fmaxf(tmax, __shfl_xor(tmax, 32));
        const float mnew = fmaxf(mrun, tmax);
        const float scale = __expf(mrun - mnew);
        #pragma unroll
        for (int hb = 0; hb < 4; ++hb) oacc[hb] *= scale;
        lrun = lrun * scale;
        mrun = mnew;

        unsigned short pb[16];
        float ps = 0.f;
        #pragma unroll
        for (int q = 0; q < 16; ++q) {
            const float p = __expf(sv[q] - mnew);
            pb[q] = f2bf(p);
            ps += bf2f(pb[q]);
        }
        ps += __shfl_xor(ps, 16);
        ps += __shfl_xor(ps, 32);
        lrun += ps;

        u16x8 pa0, pa1;
        #pragma unroll
        for (int q = 0; q < 8; ++q) { pa0[q] = pb[q]; pa1[q] = pb[8 + q]; }

        // ---- PV, operand-swapped: O^T = V^T * P^T ----
        #pragma unroll
        for (int hb = 0; hb < 4; ++hb) {
            const unsigned short* vp = &Vl[(hb * 16 + n) * 72 + 4 * g];
            const u16x4 a0 = *reinterpret_cast<const u16x4*>(vp);
            const u16x4 a1 = *reinterpret_cast<const u16x4*>(vp + 16);
            const u16x4 b0 = *reinterpret_cast<const u16x4*>(vp + 32);
            const u16x4 b1 = *reinterpret_cast<const u16x4*>(vp + 48);
            const u16x8 vf0 = { a0[0], a0[1], a0[2], a0[3], a1[0], a1[1], a1[2], a1[3] };
            const u16x8 vf1 = { b0[0], b0[1], b0[2], b0[3], b1[0], b1[1], b1[2], b1[3] };
            oacc[hb] = mfma_bf16(vf0, pa0, oacc[hb]);
            oacc[hb] = mfma_bf16(vf1, pa1, oacc[hb]);
        }
    }

    // ---- normalize + store ----
    const float inv = 1.0f / lrun;
    #pragma unroll
    for (int hb = 0; hb < 4; ++hb) {
        float4 o;
        o.x = oacc[hb][0] * inv; o.y = oacc[hb][1] * inv;
        o.z = oacc[hb][2] * inv; o.w = oacc[hb][3] * inv;
        *reinterpret_cast<float4*>(
            &out[((size_t)b * T_SEQ + qrow) * H_DIM + hb * 16 + 4 * g]) = o;
    }
}

// ---------------------------------------------------------------------------
extern "C" void kernel_launch(void* const* d_in, const int* in_sizes, int n_in,
                              void* d_out, int out_size, void* d_ws, size_t ws_size,
                              hipStream_t stream) {
    const float* x  = (const float*)d_in[0];
    const float* Wq = (const float*)d_in[1];
    const float* Wk = (const float*)d_in[2];
    const float* Wv = (const float*)d_in[3];

    unsigned short* Qg  = (unsigned short*)d_ws;
    unsigned short* Kg  = Qg + (size_t)M_TOT * H_DIM;
    unsigned short* Vtg = Kg + (size_t)M_TOT * H_DIM;
    unsigned short* Wt  = Vtg + (size_t)M_TOT * H_DIM;
    float* o = (float*)d_out;

    wtrans_kernel<<<48, 256, 0, stream>>>(Wq, Wk, Wv, Wt);
    qkv_proj_kernel<<<M_TOT / 32, 256, 0, stream>>>(x, Wt, Qg, Kg, Vtg);
    attn_kernel<<<512, 128, 0, stream>>>(Qg, Kg, Vtg, o);
}

// Round 6
// 58.023 us; speedup vs baseline: 10.2988x; 1.0760x over previous
//
#include <hip/hip_runtime.h>

#define D_DIM 1024
#define H_DIM 64
#define T_SEQ 2048
#define B_SZ  8
#define M_TOT (B_SZ * T_SEQ)

typedef __attribute__((ext_vector_type(4))) float f32x4;
typedef __attribute__((ext_vector_type(8))) short s16x8;
typedef __attribute__((ext_vector_type(8))) unsigned short u16x8;
typedef __attribute__((ext_vector_type(4))) unsigned short u16x4;

__device__ __forceinline__ unsigned short f2bf(float x) {
    union { float f; unsigned u; } v; v.f = x;
    unsigned r = (v.u + 0x7FFFu + ((v.u >> 16) & 1u)) >> 16;   // RNE
    return (unsigned short)r;
}
__device__ __forceinline__ float bf2f(unsigned short u) {
    union { unsigned u; float f; } v; v.u = ((unsigned)u) << 16; return v.f;
}

__device__ __forceinline__ f32x4 mfma_bf16(u16x8 a, u16x8 b, f32x4 c) {
    return __builtin_amdgcn_mfma_f32_16x16x32_bf16(
        __builtin_bit_cast(s16x8, a), __builtin_bit_cast(s16x8, b), c, 0, 0, 0);
}

// ---------------------------------------------------------------------------
// Kernel 0: W [1024][64] fp32 (x3) -> Wt bf16 [192][1024]  (Wt[c][k] = W[k][c])
// ---------------------------------------------------------------------------
__global__ __launch_bounds__(256) void wtrans_kernel(
    const float* __restrict__ Wq, const float* __restrict__ Wk,
    const float* __restrict__ Wv, unsigned short* __restrict__ Wt)
{
    __shared__ unsigned short tw[64 * 72];
    const int mat = blockIdx.x / 16;
    const int k0  = (blockIdx.x % 16) * 64;
    const float* W = (mat == 0) ? Wq : (mat == 1) ? Wk : Wv;
    const int tid = threadIdx.x;

    {
        const int r = tid >> 2, c0 = (tid & 3) * 16;
        #pragma unroll
        for (int jj = 0; jj < 4; ++jj) {
            float4 v = *reinterpret_cast<const float4*>(&W[(size_t)(k0 + r) * H_DIM + c0 + jj * 4]);
            u16x4 u = { f2bf(v.x), f2bf(v.y), f2bf(v.z), f2bf(v.w) };
            *reinterpret_cast<u16x4*>(&tw[r * 72 + c0 + jj * 4]) = u;
        }
    }
    __syncthreads();
    {
        const int c = tid >> 2, kc = (tid & 3) * 16;
        unsigned short tmp[16];
        #pragma unroll
        for (int kk = 0; kk < 16; ++kk) tmp[kk] = tw[(kc + kk) * 72 + c];
        #pragma unroll
        for (int h = 0; h < 2; ++h)
            *reinterpret_cast<u16x8*>(&Wt[((size_t)mat * 64 + c) * D_DIM + k0 + kc + h * 8]) =
                *reinterpret_cast<u16x8*>(&tmp[h * 8]);
    }
}

// ---------------------------------------------------------------------------
// Kernel 1: QKV projection v3: 16-row tiles, grid 1024 (4 blocks/CU,
// 16 waves/CU), BK=64, reg-staged prefetch, 4 waves x 48 cols.
// ---------------------------------------------------------------------------
__global__ __launch_bounds__(256) void qkv_proj_kernel(
    const float* __restrict__ x, const unsigned short* __restrict__ Wt,
    unsigned short* __restrict__ Qg, unsigned short* __restrict__ Kg,
    unsigned short* __restrict__ Vtg)
{
    __shared__ unsigned short xs[16 * 72];    // [16][64+pad]
    __shared__ unsigned short ws[192 * 72];   // [192][64+pad]
    __shared__ unsigned short vt[64 * 24];    // [h][16t+pad]

    const int tid = threadIdx.x;
    const int w = tid >> 6, l = tid & 63, g = l >> 4, n = l & 15;
    const int m0 = blockIdx.x * 16;

    f32x4 acc[3];
    #pragma unroll
    for (int ct = 0; ct < 3; ++ct) acc[ct] = f32x4{0.f, 0.f, 0.f, 0.f};

    // staging: x 16x64 fp32 (1 float4/thread), W 192x64 bf16 (6 u16x8/thread)
    float4 xr;
    u16x8  wr[6];
    const int sr = tid >> 4, sc = (tid & 15) * 4;
    {
        xr = *reinterpret_cast<const float4*>(&x[(size_t)(m0 + sr) * D_DIM + sc]);
        #pragma unroll
        for (int jj = 0; jj < 6; ++jj) {
            int u = tid + jj * 256, r = u >> 3, c = (u & 7) * 8;
            wr[jj] = *reinterpret_cast<const u16x8*>(&Wt[(size_t)r * D_DIM + c]);
        }
    }

    for (int ks = 0; ks < 16; ++ks) {
        __syncthreads();
        {
            u16x4 xv = { f2bf(xr.x), f2bf(xr.y), f2bf(xr.z), f2bf(xr.w) };
            *reinterpret_cast<u16x4*>(&xs[sr * 72 + sc]) = xv;
            #pragma unroll
            for (int jj = 0; jj < 6; ++jj) {
                int u = tid + jj * 256, r = u >> 3, c = (u & 7) * 8;
                *reinterpret_cast<u16x8*>(&ws[r * 72 + c]) = wr[jj];
            }
        }
        __syncthreads();
        if (ks < 15) {
            const int k0 = (ks + 1) * 64;
            xr = *reinterpret_cast<const float4*>(&x[(size_t)(m0 + sr) * D_DIM + k0 + sc]);
            #pragma unroll
            for (int jj = 0; jj < 6; ++jj) {
                int u = tid + jj * 256, r = u >> 3, c = (u & 7) * 8;
                wr[jj] = *reinterpret_cast<const u16x8*>(&Wt[(size_t)r * D_DIM + k0 + c]);
            }
        }
        #pragma unroll
        for (int kh = 0; kh < 2; ++kh) {
            const u16x8 af = *reinterpret_cast<const u16x8*>(&xs[n * 72 + kh * 32 + g * 8]);
            u16x8 bfr[3];
            #pragma unroll
            for (int ct = 0; ct < 3; ++ct)
                bfr[ct] = *reinterpret_cast<const u16x8*>(&ws[(w * 48 + ct * 16 + n) * 72 + kh * 32 + g * 8]);
            #pragma unroll
            for (int ct = 0; ct < 3; ++ct)
                acc[ct] = mfma_bf16(af, bfr[ct], acc[ct]);
        }
    }

    // epilogue: D layout col = lane&15, row = (lane>>4)*4 + reg
    const int b = m0 >> 11, t0 = m0 & (T_SEQ - 1);
    #pragma unroll
    for (int ct = 0; ct < 3; ++ct) {
        const int c = w * 48 + ct * 16 + n;
        #pragma unroll
        for (int r = 0; r < 4; ++r) {
            const int rin = g * 4 + r;
            const float val = acc[ct][r];
            if (c < 64)
                Qg[(size_t)(m0 + rin) * H_DIM + c] = f2bf(val * 0.125f);
            else if (c < 128)
                Kg[(size_t)(m0 + rin) * H_DIM + (c - 64)] = f2bf(val);
            else
                vt[(c - 128) * 24 + rin] = f2bf(val);
        }
    }
    __syncthreads();
    {   // Vt[b][h][t] coalesced: 64h x 16t = 1 u16x4/thread
        const int h = tid >> 2, c4 = (tid & 3) * 4;
        *reinterpret_cast<u16x4*>(&Vtg[((size_t)(b * 64 + h)) * T_SEQ + t0 + c4]) =
            *reinterpret_cast<const u16x4*>(&vt[h * 24 + c4]);
    }
}

// ---------------------------------------------------------------------------
// Kernel 2: causal flash attention v2.
// Block = 32 queries x 4 waves: wave = (qg, kh); qg picks 16 queries, kh
// picks a 64-key half of each 128-key LDS tile. End-merge (m,l,oacc)
// between kh pairs via LDS. QK^T and PV both operand-swapped.
// ---------------------------------------------------------------------------
__global__ __launch_bounds__(256) void attn_kernel(
    const unsigned short* __restrict__ Qg, const unsigned short* __restrict__ Kg,
    const unsigned short* __restrict__ Vtg, float* __restrict__ out)
{
    __shared__ unsigned short Kl[128 * 72];   // [key][h]
    __shared__ unsigned short Vl[64 * 136];   // [h][key]
    __shared__ float Om[2][64][20];           // merge buffer
    __shared__ float mred[4][64], lred[4][64];

    const int tid = threadIdx.x;
    const int wv = tid >> 6, qg = wv >> 1, kh = wv & 1;
    const int l = tid & 63, g = l >> 4, n = l & 15;

    const int i = blockIdx.x, hi = i >> 8, rest = i & 255;
    const int b = hi * 4 + (rest >> 6), j = rest & 63;
    const int qt = hi ? (63 - j) : j;
    const int q0 = qt * 32;
    const int qrow = q0 + qg * 16 + n;
    const int qmax = q0 + qg * 16 + 15;       // max qrow in this wave
    const int nk = (qt >> 2) + 1;             // # of 128-key tiles

    const unsigned short* Qb = Qg + (size_t)b * T_SEQ * H_DIM;
    const unsigned short* Kb = Kg + (size_t)b * T_SEQ * H_DIM;
    const unsigned short* Vb = Vtg + (size_t)b * H_DIM * T_SEQ;

    const u16x8 qf0 = *reinterpret_cast<const u16x8*>(&Qb[(size_t)qrow * H_DIM + g * 8]);
    const u16x8 qf1 = *reinterpret_cast<const u16x8*>(&Qb[(size_t)qrow * H_DIM + 32 + g * 8]);

    f32x4 oacc[4];
    #pragma unroll
    for (int hb = 0; hb < 4; ++hb) oacc[hb] = f32x4{0.f, 0.f, 0.f, 0.f};
    float mrun = -1e30f, lrun = 0.f;

    // staging regs: K 128x64, V 64x128 (4 u16x8/thread each)
    u16x8 kst[4], vst[4];
    #pragma unroll
    for (int ii = 0; ii < 4; ++ii) {
        const int u = tid + ii * 256;
        const int kr = u >> 3, kc = (u & 7) * 8;
        const int vh = u >> 4, vc = (u & 15) * 8;
        kst[ii] = *reinterpret_cast<const u16x8*>(&Kb[(size_t)kr * H_DIM + kc]);
        vst[ii] = *reinterpret_cast<const u16x8*>(&Vb[(size_t)vh * T_SEQ + vc]);
    }

    for (int t = 0; t < nk; ++t) {
        __syncthreads();
        #pragma unroll
        for (int ii = 0; ii < 4; ++ii) {
            const int u = tid + ii * 256;
            const int kr = u >> 3, kc = (u & 7) * 8;
            const int vh = u >> 4, vc = (u & 15) * 8;
            *reinterpret_cast<u16x8*>(&Kl[kr * 72 + kc]) = kst[ii];
            *reinterpret_cast<u16x8*>(&Vl[vh * 136 + vc]) = vst[ii];
        }
        __syncthreads();
        if (t + 1 < nk) {
            const int k0n = (t + 1) * 128;
            #pragma unroll
            for (int ii = 0; ii < 4; ++ii) {
                const int u = tid + ii * 256;
                const int kr = u >> 3, kc = (u & 7) * 8;
                const int vh = u >> 4, vc = (u & 15) * 8;
                kst[ii] = *reinterpret_cast<const u16x8*>(&Kb[(size_t)(k0n + kr) * H_DIM + kc]);
                vst[ii] = *reinterpret_cast<const u16x8*>(&Vb[(size_t)vh * T_SEQ + k0n + vc]);
            }
        }

        const int kbase = kh * 64;                 // this wave's key half (in LDS)
        if (t * 128 + kbase <= qmax) {             // wave-uniform: any valid key?
            // ---- swapped QK^T: S^T[key][q] ----
            f32x4 s[4];
            #pragma unroll
            for (int kb = 0; kb < 4; ++kb) {
                const u16x8 kf0 = *reinterpret_cast<const u16x8*>(&Kl[(kbase + kb * 16 + n) * 72 + g * 8]);
                const u16x8 kf1 = *reinterpret_cast<const u16x8*>(&Kl[(kbase + kb * 16 + n) * 72 + 32 + g * 8]);
                f32x4 z = f32x4{0.f, 0.f, 0.f, 0.f};
                z = mfma_bf16(kf0, qf0, z);
                z = mfma_bf16(kf1, qf1, z);
                s[kb] = z;
            }

            // ---- mask + online softmax ----
            float sv[16];
            float tmax = -1e30f;
            #pragma unroll
            for (int kb = 0; kb < 4; ++kb)
                #pragma unroll
                for (int r = 0; r < 4; ++r) {
                    const int kk = t * 128 + kbase + kb * 16 + g * 4 + r;
                    float v = s[kb][r];
                    v = (kk <= qrow) ? v : -1e30f;
                    sv[kb * 4 + r] = v;
                    tmax = fmaxf(tmax, v);
                }
            tmax = fmaxf(tmax, __shfl_xor(tmax, 16));
            tmax = fmaxf(tmax, __shfl_xor(tmax, 32));
            const float mnew = fmaxf(mrun, tmax);
            const float scale = __expf(mrun - mnew);
            #pragma unroll
            for (int hb = 0; hb < 4; ++hb) oacc[hb] *= scale;
            lrun = lrun * scale;
            mrun = mnew;

            unsigned short pb[16];
            float ps = 0.f;
            #pragma unroll
            for (int q = 0; q < 16; ++q) {
                // guard: all-masked lanes keep mnew=-1e30; exp(0) would be 1
                const float p = (sv[q] > -1e29f) ? __expf(sv[q] - mnew) : 0.f;
                pb[q] = f2bf(p);
                ps += bf2f(pb[q]);
            }
            ps += __shfl_xor(ps, 16);
            ps += __shfl_xor(ps, 32);
            lrun += ps;

            u16x8 pa0, pa1;
            #pragma unroll
            for (int q = 0; q < 8; ++q) { pa0[q] = pb[q]; pa1[q] = pb[8 + q]; }

            // ---- PV, operand-swapped: O^T = V^T * P^T ----
            #pragma unroll
            for (int hb = 0; hb < 4; ++hb) {
                const unsigned short* vp = &Vl[(hb * 16 + n) * 136 + kbase + 4 * g];
                const u16x4 a0 = *reinterpret_cast<const u16x4*>(vp);
                const u16x4 a1 = *reinterpret_cast<const u16x4*>(vp + 16);
                const u16x4 b0 = *reinterpret_cast<const u16x4*>(vp + 32);
                const u16x4 b1 = *reinterpret_cast<const u16x4*>(vp + 48);
                const u16x8 vf0 = { a0[0], a0[1], a0[2], a0[3], a1[0], a1[1], a1[2], a1[3] };
                const u16x8 vf1 = { b0[0], b0[1], b0[2], b0[3], b1[0], b1[1], b1[2], b1[3] };
                oacc[hb] = mfma_bf16(vf0, pa0, oacc[hb]);
                oacc[hb] = mfma_bf16(vf1, pa1, oacc[hb]);
            }
        }
    }

    // ---- cross-wave (kh pair) merge ----
    mred[wv][l] = mrun;
    lred[wv][l] = lrun;
    __syncthreads();
    const float m0v = mred[qg * 2][l],     l0v = lred[qg * 2][l];
    const float m1v = mred[qg * 2 + 1][l], l1v = lred[qg * 2 + 1][l];
    const float M = fmaxf(m0v, m1v);
    const float alpha = __expf(mrun - M);       // own rescale (0 if all-masked)
    const float Lsum = l0v * __expf(m0v - M) + l1v * __expf(m1v - M);
    #pragma unroll
    for (int hb = 0; hb < 4; ++hb) oacc[hb] *= alpha;

    if (kh == 1) {
        #pragma unroll
        for (int hb = 0; hb < 4; ++hb)
            *reinterpret_cast<f32x4*>(&Om[qg][l][hb * 4]) = oacc[hb];
    }
    __syncthreads();
    if (kh == 0) {
        const float inv = 1.0f / Lsum;          // >0: key 0 valid for every row
        #pragma unroll
        for (int hb = 0; hb < 4; ++hb) {
            const f32x4 o2 = *reinterpret_cast<const f32x4*>(&Om[qg][l][hb * 4]);
            float4 o;
            o.x = (oacc[hb][0] + o2[0]) * inv;
            o.y = (oacc[hb][1] + o2[1]) * inv;
            o.z = (oacc[hb][2] + o2[2]) * inv;
            o.w = (oacc[hb][3] + o2[3]) * inv;
            *reinterpret_cast<float4*>(
                &out[((size_t)b * T_SEQ + qrow) * H_DIM + hb * 16 + 4 * g]) = o;
        }
    }
}

// ---------------------------------------------------------------------------
extern "C" void kernel_launch(void* const* d_in, const int* in_sizes, int n_in,
                              void* d_out, int out_size, void* d_ws, size_t ws_size,
                              hipStream_t stream) {
    const float* x  = (const float*)d_in[0];
    const float* Wq = (const float*)d_in[1];
    const float* Wk = (const float*)d_in[2];
    const float* Wv = (const float*)d_in[3];

    unsigned short* Qg  = (unsigned short*)d_ws;
    unsigned short* Kg  = Qg + (size_t)M_TOT * H_DIM;
    unsigned short* Vtg = Kg + (size_t)M_TOT * H_DIM;
    unsigned short* Wt  = Vtg + (size_t)M_TOT * H_DIM;
    float* o = (float*)d_out;

    wtrans_kernel<<<48, 256, 0, stream>>>(Wq, Wk, Wv, Wt);
    qkv_proj_kernel<<<M_TOT / 16, 256, 0, stream>>>(x, Wt, Qg, Kg, Vtg);
    attn_kernel<<<512, 256, 0, stream>>>(Qg, Kg, Vtg, o);
}